// Round 9
// baseline (557.723 us; speedup 1.0000x reference)
//
#include <hip/hip_runtime.h>

// ConvCRF forward, MI355X — round 9: diagonal fast path + register weights +
// f32 LDS taps + 4 barriers.
// R8 post-mortem: crf 69us, ~12us/iter vs ~3us work; LDS pipe ~172 ops/thr/iter
// (49 wbH + 49 smH + 72 accF + matvec broadcasts) + 880 VALU (f16 cvts).
// Fixes:
//  - prep detects Ms/Mb exactly diagonal (true for these inputs: compat@eye).
//    Fast path: pairwise is channel-local -> accF exchange + 19x40 matvec
//    + 2 syncthreads per iter all vanish. General path retained.
//  - 49 tap weights (packed half2) loaded into VGPRs once -> no per-iter wbH reads.
//  - sm halo staged as f32 float4 (cvt once at staging, not 4x/tap);
//    taps = ds_read_b128 + 2 cvt + 12 fma (ext-vector ops -> v_pk_fma_f32).
//  - iteration 0 computes halo softmax straight from u: no initial publish,
//    no barrier 0 -> 4 barriers.
// Proven pieces kept: 200-block grid, fence-free barrier via relaxed agent
// atomics (gsm sc0sc1 coherent at IF$; __syncthreads drains vmcnt before
// the counter add), f16 gsm exchange, batch algebra (sm1 = 1-sm0).

typedef __attribute__((ext_vector_type(4))) _Float16 half4;
typedef __attribute__((ext_vector_type(2))) _Float16 half2f;
typedef __attribute__((ext_vector_type(4))) float float4v;

#define HH 160
#define WW 160
#define NPIX (HH*WW)
#define NC 19
#define NG 5
#define SPAN 3
#define TR 8
#define TC 16
#define NPXT 128
#define LR 14              // TR + 2*SPAN
#define LC 22              // TC + 2*SPAN
#define LCP 25             // padded halo row stride (float4 units)
#define HSTRIDE (LR*LCP)   // 350
#define NHALO (LR*LC)      // 308
#define NBLK 200
#define NTHR 640
#define EPSF 1e-20f
#define MAGICV 0x5EEDF00Du

// LDS: region A (30,720B) time-shared: rgbL(2x350 f4 = 11,200) ->
//      smF(5x350 f4 = 28,000) -> accF(60x128 f32 = 30,720, general path only).
//      wbH (49x128 u32 = 25,088) read once into registers.
#define SZ_A    30720
#define OFF_WB  SZ_A
#define LDS_TOT (SZ_A + 49*128*4)   // 55,808

__device__ __forceinline__ float fast_rcp(float x) { return __builtin_amdgcn_rcpf(x); }

__device__ __forceinline__ float smx0(float q0, float q1) {
    const float m  = fmaxf(q0, q1);
    const float e0 = __expf(q0 - m);
    const float e1 = __expf(q1 - m);
    return e0 * fast_rcp(e0 + e1);
}

// M layout (floats): [0..959] 20x48 rows [Ms|Mb|RS|pad]; [960..979] diag(Ms);
// [980..999] diag(Mb); [1000] diag-flag.
__global__ __launch_bounds__(960) void prep_kernel(
        const float* __restrict__ sw, const float* __restrict__ bw,
        const float* __restrict__ compat, float* __restrict__ M) {
    __shared__ float Msh[960];
    __shared__ int   diag;
    const int e = threadIdx.x;
    if (e == 0) diag = 1;
    __syncthreads();
    const int k = e / 48, c = e % 48;
    float acc = 0.0f;
    if (k < NC) {
        if (c < NC) {
            for (int j = 0; j < NC; ++j) acc += compat[k*NC + j] * sw[j*NC + c];
        } else if (c >= 20 && c < 20 + NC) {
            const int cc = c - 20;
            for (int j = 0; j < NC; ++j) acc += compat[k*NC + j] * bw[j*NC + cc];
        } else if (c == 40) {
            for (int j = 0; j < NC; ++j) {
                float rs = 0.0f;
                for (int cc = 0; cc < NC; ++cc) rs += sw[j*NC + cc] + bw[j*NC + cc];
                acc += compat[k*NC + j] * rs;
            }
        }
    }
    Msh[e] = acc;
    bool off = false;
    if (k < NC) {
        if (c < NC && c != k && acc != 0.0f) off = true;
        if (c >= 20 && c < 20 + NC && (c - 20) != k && acc != 0.0f) off = true;
    }
    if (off) atomicAnd(&diag, 0);
    __syncthreads();
    M[e] = acc;
    if (e < 20) {
        M[960 + e] = Msh[e*48 + e];                       // diag(Ms), row19 pad=0
        M[980 + e] = (e < NC) ? Msh[e*48 + 20 + e] : 0.f; // diag(Mb)
    }
    if (e == 0) M[1000] = (float)diag;
}

__global__ void __launch_bounds__(NTHR) crf_kernel(
        const float* __restrict__ u,
        const float* __restrict__ rgb,
        const float* __restrict__ M,
        unsigned long long* __restrict__ gsm,   // sm0 field [g][NPIX], half4-as-u64
        unsigned* __restrict__ bar,
        float* __restrict__ out) {
    __shared__ __align__(16) char shm[LDS_TOT];
    float4*   rgbL = (float4*)shm;               // prologue only
    float4v*  smF  = (float4v*)shm;              // per-iter sm halo (f32)
    float*    accF = (float*)shm;                // general-path epilogue
    unsigned* wbH  = (unsigned*)(shm + OFF_WB);  // prologue only (read to regs)

    constexpr float WSPC[49] = {
        0.36787944f,0.48567179f,0.57375342f,0.60653066f,0.57375342f,0.48567179f,0.36787944f,
        0.48567179f,0.64118039f,0.75746513f,0.80073740f,0.75746513f,0.64118039f,0.48567179f,
        0.57375342f,0.75746513f,0.89483932f,0.94595947f,0.89483932f,0.75746513f,0.57375342f,
        0.60653066f,0.80073740f,0.94595947f,1.00000000f,0.94595947f,0.80073740f,0.60653066f,
        0.57375342f,0.75746513f,0.89483932f,0.94595947f,0.89483932f,0.75746513f,0.57375342f,
        0.48567179f,0.64118039f,0.75746513f,0.80073740f,0.75746513f,0.64118039f,0.48567179f,
        0.36787944f,0.48567179f,0.57375342f,0.60653066f,0.57375342f,0.48567179f,0.36787944f };

    const int tid = threadIdx.x;
    const int px  = tid & 127;
    const int g   = tid >> 7;
    const int r   = px >> 4, c = px & 15;
    const int ti0 = blockIdx.y * TR, tj0 = blockIdx.x * TC;
    const int gp  = (ti0 + r) * WW + (tj0 + c);
    const int ctr = (r + SPAN) * LCP + (c + SPAN);
    const int ku  = 4 * __builtin_amdgcn_readfirstlane(g);

    // ---- barrier init handshake ----
    if ((blockIdx.x | blockIdx.y) == 0 && tid == 0) {
        __hip_atomic_store(&bar[1], 0u, __ATOMIC_RELAXED, __HIP_MEMORY_SCOPE_AGENT);
        __hip_atomic_store(&bar[0], MAGICV, __ATOMIC_RELEASE, __HIP_MEMORY_SCOPE_AGENT);
    }
    if (tid == 0) {
        while (__hip_atomic_load(&bar[0], __ATOMIC_ACQUIRE, __HIP_MEMORY_SCOPE_AGENT) != MAGICV)
            __builtin_amdgcn_s_sleep(2);
    }
    __syncthreads();

    // ---- phase 1: rgb halo, both batches ----
    for (int e = tid; e < 2 * NHALO; e += NTHR) {
        const int bb = e / NHALO, pos = e % NHALO;
        const int hr = pos / LC, hc = pos % LC;
        const int yi = ti0 - SPAN + hr, xj = tj0 - SPAN + hc;
        float4 rv = make_float4(0.f, 0.f, 0.f, 0.f);
        if ((unsigned)yi < HH && (unsigned)xj < WW) {
            const float* p = rgb + ((size_t)(bb * NPIX) + yi * WW + xj) * 3;
            rv = make_float4(p[0]*(1.f/160.f), p[1]*(1.f/160.f), p[2]*(1.f/160.f), 1.f);
        }
        rgbL[bb * HSTRIDE + hr * LCP + hc] = rv;
    }
    __syncthreads();

    // ---- phase 2a: bilateral weights, tap-subset per channel group ----
    {
        const float4 cv0 = rgbL[ctr];
        const float4 cv1 = rgbL[HSTRIDE + ctr];
        const int tapb = g * 10;
        const int ntap = (g == 4) ? 9 : 10;
        for (int i = 0; i < ntap; ++i) {
            const int t = tapb + i;
            const int dx = t / 7 - SPAN, dy = t % 7 - SPAN;
            const int n = ctr + dx * LCP + dy;
            const float4 nv0 = rgbL[n];
            const float4 nv1 = rgbL[HSTRIDE + n];
            const float wsm = __expf(-(float)(dx*dx + dy*dy) * (1.f/18.f)) * nv0.w;
            const float dr0 = cv0.x-nv0.x, dg0 = cv0.y-nv0.y, db0 = cv0.z-nv0.z;
            const float dr1 = cv1.x-nv1.x, dg1 = cv1.y-nv1.y, db1 = cv1.z-nv1.z;
            const float wb0 = wsm * __expf(-0.5f*(dr0*dr0+dg0*dg0+db0*db0));
            const float wb1 = wsm * __expf(-0.5f*(dr1*dr1+dg1*dg1+db1*db1));
            half2f hw = {(_Float16)wb0, (_Float16)wb1};
            unsigned uw; __builtin_memcpy(&uw, &hw, 4);
            wbH[t*NPXT + px] = uw;
        }
    }
    __syncthreads();

    // ---- phase 2b: weights -> 49 VGPRs; inverse norms ----
    unsigned w49[49];
    float snI, bnI0, bnI1;
    {
        float sn = 0.f, bn0 = 0.f, bn1 = 0.f;
        #pragma unroll
        for (int t = 0; t < 49; ++t) {
            w49[t] = wbH[t*NPXT + px];
            half2f hw; __builtin_memcpy(&hw, &w49[t], 4);
            bn0 += (float)hw.x; bn1 += (float)hw.y;
            const int dx = t / 7 - SPAN, dy = t % 7 - SPAN;
            const int yi = ti0 + r + dx, xj = tj0 + c + dy;
            sn += (((unsigned)yi < HH) && ((unsigned)xj < WW)) ? WSPC[t] : 0.0f;
        }
        snI  = fast_rcp(sn + EPSF);
        bnI0 = fast_rcp(bn0 + EPSF);
        bnI1 = fast_rcp(bn1 + EPSF);
    }

    // ---- one-time: unaries, diag coefficients, path flag (all uniform loads) ----
    float uv0[4], uv1[4], dsv[4], dbv[4];
    #pragma unroll
    for (int i = 0; i < 4; ++i) {
        const int ch = 4*g + i;
        uv0[i] = (ch < NC) ? u[(size_t)gp * NC + ch] : 0.0f;
        uv1[i] = (ch < NC) ? u[((size_t)NPIX + gp) * NC + ch] : 0.0f;
        dsv[i] = M[960 + ku + i];
        dbv[i] = M[980 + ku + i];
    }
    const bool isdiag = (M[1000] != 0.0f);

    for (int it = 0; it < 5; ++it) {
        if (it > 0) {   // fence-free grid barrier (syncthreads drains vmcnt)
            __syncthreads();
            if (tid == 0) {
                __hip_atomic_fetch_add(&bar[1], 1u, __ATOMIC_RELAXED, __HIP_MEMORY_SCOPE_AGENT);
                while (__hip_atomic_load(&bar[1], __ATOMIC_RELAXED, __HIP_MEMORY_SCOPE_AGENT)
                       < (unsigned)(NBLK * it))
                    __builtin_amdgcn_s_sleep(2);
            }
            __syncthreads();
        }

        // ---- stage sm0 halo as f32 float4 ----
        #pragma unroll
        for (int k2 = 0; k2 < 3; ++k2) {
            const int e = tid + NTHR * k2;
            if (e < NG * NHALO) {
                const int sg = e / NHALO, pos = e - sg * NHALO;
                const int hr = pos / LC, hc = pos - hr * LC;
                const int yi = ti0 - SPAN + hr, xj = tj0 - SPAN + hc;
                float4v o = (float4v)0.0f;
                if ((unsigned)yi < HH && (unsigned)xj < WW) {
                    const int p = yi * WW + xj;
                    if (it == 0) {
                        const float* q0 = u + (size_t)p * NC;
                        const float* q1 = u + (size_t)(NPIX + p) * NC;
                        #pragma unroll
                        for (int i = 0; i < 4; ++i) {
                            const int ch = 4*sg + i;
                            const float a = (ch < NC) ? q0[ch] : 0.0f;
                            const float d = (ch < NC) ? q1[ch] : 0.0f;
                            o[i] = smx0(a, d);
                        }
                    } else {
                        const unsigned long long raw =
                            __hip_atomic_load(&gsm[sg * NPIX + p],
                                              __ATOMIC_RELAXED, __HIP_MEMORY_SCOPE_AGENT);
                        half4 hv; __builtin_memcpy(&hv, &raw, 8);
                        #pragma unroll
                        for (int i = 0; i < 4; ++i) o[i] = (float)hv[i];
                    }
                }
                smF[sg * HSTRIDE + hr * LCP + hc] = o;
            }
        }
        __syncthreads();

        // ---- 49 taps: ds_read_b128 + 2 cvt + 12 fma (vector ops) ----
        float4v sAv = (float4v)0.0f, b0a = (float4v)0.0f, b1a = (float4v)0.0f;
        const float4v* pl = smF + g * HSTRIDE;
        #pragma unroll
        for (int dx = -SPAN; dx <= SPAN; ++dx) {
            #pragma unroll
            for (int dy = -SPAN; dy <= SPAN; ++dy) {
                const int t = (dx+SPAN)*7 + (dy+SPAN);
                half2f hw; __builtin_memcpy(&hw, &w49[t], 4);
                const float w0 = (float)hw.x, w1 = (float)hw.y;
                const float4v v = pl[ctr + dx*LCP + dy];
                sAv += WSPC[t] * v;
                b0a += w0 * v;
                b1a += w1 * v;
            }
        }

        float q0v[4], q1v[4];
        if (isdiag) {
            // ---- fast path: channel-local pairwise; no LDS, no syncs ----
            #pragma unroll
            for (int i = 0; i < 4; ++i) {
                const float sAn = sAv[i] * snI;
                const float b0n = b0a[i] * bnI0;
                const float b1x = b1a[i] * bnI1;
                q0v[i] = uv0[i] - dsv[i]*sAn - dbv[i]*b0n;
                q1v[i] = uv1[i] - (dsv[i] + dbv[i]) + dsv[i]*sAn + dbv[i]*b1x;
            }
        } else {
            // ---- general path: cross-channel matvec via accF + s_load M ----
            __syncthreads();   // smF dead -> region A becomes accF
            #pragma unroll
            for (int i = 0; i < 4; ++i) {
                accF[(4*g + i) * NPXT + px]      = sAv[i] * snI;
                accF[(20 + 4*g + i) * NPXT + px] = b0a[i] * bnI0;
                accF[(40 + 4*g + i) * NPXT + px] = b1a[i] * bnI1;
            }
            __syncthreads();
            float t1[4] = {0,0,0,0}, t2[4] = {0,0,0,0}, t3[4] = {0,0,0,0};
            #pragma unroll
            for (int cc = 0; cc < 20; ++cc) {
                const float sv  = accF[cc * NPXT + px];
                const float b0v = accF[(20 + cc) * NPXT + px];
                const float b1v = accF[(40 + cc) * NPXT + px];
                #pragma unroll
                for (int i = 0; i < 4; ++i) {
                    const float* mk = M + (ku + i) * 48;
                    t1[i] += mk[cc] * sv;
                    t2[i] += mk[20 + cc] * b0v;
                    t3[i] += mk[20 + cc] * b1v;
                }
            }
            #pragma unroll
            for (int i = 0; i < 4; ++i) {
                const float rs = M[(ku + i) * 48 + 40];
                q0v[i] = uv0[i] - t1[i] - t2[i];
                q1v[i] = uv1[i] - rs + t1[i] + t3[i];
            }
        }

        if (it == 4) {
            #pragma unroll
            for (int i = 0; i < 4; ++i) {
                const int ch = 4*g + i;
                if (ch < NC) {
                    out[(size_t)gp * NC + ch]          = q0v[i];
                    out[((size_t)NPIX + gp) * NC + ch] = q1v[i];
                }
            }
        } else {
            half4 sh;
            #pragma unroll
            for (int i = 0; i < 4; ++i) sh[i] = (_Float16)smx0(q0v[i], q1v[i]);
            unsigned long long u64; __builtin_memcpy(&u64, &sh, 8);
            __hip_atomic_store(&gsm[g * NPIX + gp], u64, __ATOMIC_RELAXED, __HIP_MEMORY_SCOPE_AGENT);
        }
    }
}

extern "C" void kernel_launch(void* const* d_in, const int* in_sizes, int n_in,
                              void* d_out, int out_size, void* d_ws, size_t ws_size,
                              hipStream_t stream) {
    const float* u      = (const float*)d_in[0];
    const float* rgb    = (const float*)d_in[1];
    const float* sw     = (const float*)d_in[2];
    const float* bw     = (const float*)d_in[3];
    const float* compat = (const float*)d_in[4];
    float* out = (float*)d_out;

    unsigned long long* gsm = (unsigned long long*)d_ws;     // 1,024,000 B
    float*    M   = (float*)((char*)d_ws + 1024000);         // 4,104 B used
    unsigned* bar = (unsigned*)((char*)d_ws + 1032192);      // flag + counter

    prep_kernel<<<1, 960, 0, stream>>>(sw, bw, compat, M);
    crf_kernel<<<dim3(WW/TC, HH/TR, 1), dim3(NTHR), 0, stream>>>(
        u, rgb, M, gsm, bar, out);
}

// Round 10
// 129.721 us; speedup vs baseline: 4.2994x; 4.2994x over previous
//
#include <hip/hip_runtime.h>

// ConvCRF forward, MI355X — round 10: R8 skeleton (no spill) + verified diag
// fast path + 4 barriers + ping-pong exchange + paired weight reads.
// R9 post-mortem: w49[49] register array -> scratch spill (FETCH 13.7->508MB,
// crf 486us). Weights stay in LDS this round; everything else that R9 verified
// (diag algebra, direct-u iter0 staging) is kept.
// Proven pieces: 200-block grid, fence-free barrier (relaxed agent atomics on
// IF$-coherent path; __syncthreads drains vmcnt), f16 sm exchange, batch
// algebra sm1 = 1-sm0 (only sm0 crosses blocks).

typedef __attribute__((ext_vector_type(4))) _Float16 half4;
typedef __attribute__((ext_vector_type(2))) _Float16 half2f;
typedef __attribute__((ext_vector_type(4))) float float4v;

#define HH 160
#define WW 160
#define NPIX (HH*WW)
#define NC 19
#define NG 5
#define SPAN 3
#define TR 8
#define TC 16
#define NPXT 128
#define LR 14              // TR + 2*SPAN
#define LC 22              // TC + 2*SPAN
#define LCP 24             // padded halo row stride (half4 units)
#define HSTRIDE (LR*LCP)   // 336
#define NHALO (LR*LC)      // 308
#define NBLK 200
#define NTHR 640
#define EPSF 1e-20f
#define MAGICV 0x5EEDF00Du

// LDS: region A (30,720B) time-shared: rgbL(2x336 f4=10,752) -> smH(5x336
// h4=13,440) -> accF(60x128 f32=30,720; general path only). wbP = 25 uint2
// pairs x 128 px = 25,600B.
#define SZ_A    30720
#define OFF_WB  SZ_A
#define LDS_TOT (SZ_A + 25*128*8)   // 56,320 -> 2 blocks/CU (112.6KB < 160KB)

__device__ __forceinline__ float fast_rcp(float x) { return __builtin_amdgcn_rcpf(x); }

__device__ __forceinline__ float smx0(float q0, float q1) {
    const float m  = fmaxf(q0, q1);
    const float e0 = __expf(q0 - m);
    const float e1 = __expf(q1 - m);
    return e0 * fast_rcp(e0 + e1);
}

// M layout (floats): [0..959] 20x48 rows [Ms|Mb|RS|pad]; [960..979] diag(Ms);
// [980..999] diag(Mb); [1000] diag-flag.
__global__ __launch_bounds__(960) void prep_kernel(
        const float* __restrict__ sw, const float* __restrict__ bw,
        const float* __restrict__ compat, float* __restrict__ M) {
    __shared__ float Msh[960];
    __shared__ int   diag;
    const int e = threadIdx.x;
    if (e == 0) diag = 1;
    __syncthreads();
    const int k = e / 48, c = e % 48;
    float acc = 0.0f;
    if (e < 960 && k < NC) {
        if (c < NC) {
            for (int j = 0; j < NC; ++j) acc += compat[k*NC + j] * sw[j*NC + c];
        } else if (c >= 20 && c < 20 + NC) {
            const int cc = c - 20;
            for (int j = 0; j < NC; ++j) acc += compat[k*NC + j] * bw[j*NC + cc];
        } else if (c == 40) {
            for (int j = 0; j < NC; ++j) {
                float rs = 0.0f;
                for (int cc = 0; cc < NC; ++cc) rs += sw[j*NC + cc] + bw[j*NC + cc];
                acc += compat[k*NC + j] * rs;
            }
        }
    }
    if (e < 960) Msh[e] = acc;
    bool off = false;
    if (e < 960 && k < NC) {
        if (c < NC && c != k && acc != 0.0f) off = true;
        if (c >= 20 && c < 20 + NC && (c - 20) != k && acc != 0.0f) off = true;
    }
    if (off) atomicAnd(&diag, 0);
    __syncthreads();
    if (e < 960) M[e] = acc;
    if (e < 20) {
        M[960 + e] = Msh[e*48 + e];
        M[980 + e] = (e < NC) ? Msh[e*48 + 20 + e] : 0.0f;
    }
    if (e == 0) M[1000] = (float)diag;
}

__global__ void __launch_bounds__(NTHR) crf_kernel(
        const float* __restrict__ u,
        const float* __restrict__ rgb,
        const float* __restrict__ M,
        unsigned long long* __restrict__ gsmA,   // ping-pong sm0 fields
        unsigned long long* __restrict__ gsmB,
        unsigned* __restrict__ bar,
        float* __restrict__ out) {
    __shared__ __align__(16) char shm[LDS_TOT];
    float4*   rgbL = (float4*)shm;               // prologue only
    half4*    smH  = (half4*)shm;                // per-iter sm0 halo (f16)
    float*    accF = (float*)shm;                // general-path epilogue
    unsigned* wbW  = (unsigned*)(shm + OFF_WB);  // u32 view for writes
    const uint2* wbP = (const uint2*)(shm + OFF_WB);  // pair view for reads

    constexpr float WSPC[49] = {
        0.36787944f,0.48567179f,0.57375342f,0.60653066f,0.57375342f,0.48567179f,0.36787944f,
        0.48567179f,0.64118039f,0.75746513f,0.80073740f,0.75746513f,0.64118039f,0.48567179f,
        0.57375342f,0.75746513f,0.89483932f,0.94595947f,0.89483932f,0.75746513f,0.57375342f,
        0.60653066f,0.80073740f,0.94595947f,1.00000000f,0.94595947f,0.80073740f,0.60653066f,
        0.57375342f,0.75746513f,0.89483932f,0.94595947f,0.89483932f,0.75746513f,0.57375342f,
        0.48567179f,0.64118039f,0.75746513f,0.80073740f,0.75746513f,0.64118039f,0.48567179f,
        0.36787944f,0.48567179f,0.57375342f,0.60653066f,0.57375342f,0.48567179f,0.36787944f };

    const int tid = threadIdx.x;
    const int px  = tid & 127;
    const int g   = tid >> 7;
    const int r   = px >> 4, c = px & 15;
    const int ti0 = blockIdx.y * TR, tj0 = blockIdx.x * TC;
    const int gp  = (ti0 + r) * WW + (tj0 + c);
    const int ctr = (r + SPAN) * LCP + (c + SPAN);
    const int ku  = 4 * __builtin_amdgcn_readfirstlane(g);

    // ---- barrier init handshake (ws poisoned 0xAA before every launch) ----
    if ((blockIdx.x | blockIdx.y) == 0 && tid == 0) {
        __hip_atomic_store(&bar[1], 0u, __ATOMIC_RELAXED, __HIP_MEMORY_SCOPE_AGENT);
        __hip_atomic_store(&bar[0], MAGICV, __ATOMIC_RELEASE, __HIP_MEMORY_SCOPE_AGENT);
    }
    if (tid == 0) {
        while (__hip_atomic_load(&bar[0], __ATOMIC_ACQUIRE, __HIP_MEMORY_SCOPE_AGENT) != MAGICV)
            __builtin_amdgcn_s_sleep(2);
    }
    __syncthreads();

    // ---- phase 1: rgb halo, both batches (scaled 1/160, .w = validity) ----
    for (int e = tid; e < 2 * NHALO; e += NTHR) {
        const int bb = e / NHALO, pos = e % NHALO;
        const int hr = pos / LC, hc = pos % LC;
        const int yi = ti0 - SPAN + hr, xj = tj0 - SPAN + hc;
        float4 rv = make_float4(0.f, 0.f, 0.f, 0.f);
        if ((unsigned)yi < HH && (unsigned)xj < WW) {
            const float* p = rgb + ((size_t)(bb * NPIX) + yi * WW + xj) * 3;
            rv = make_float4(p[0]*(1.f/160.f), p[1]*(1.f/160.f), p[2]*(1.f/160.f), 1.f);
        }
        rgbL[(bb ? HSTRIDE : 0) + hr * LCP + hc] = rv;
    }
    __syncthreads();

    // ---- phase 2a: bilateral weights (tap-subset per group) -> LDS pairs ----
    {
        const float4 cv0 = rgbL[ctr];
        const float4 cv1 = rgbL[HSTRIDE + ctr];
        const int tapb = g * 10;
        const int ntap = (g == 4) ? 9 : 10;
        for (int i = 0; i < ntap; ++i) {
            const int t = tapb + i;
            const int dx = t / 7 - SPAN, dy = t % 7 - SPAN;
            const int n = ctr + dx * LCP + dy;
            const float4 nv0 = rgbL[n];
            const float4 nv1 = rgbL[HSTRIDE + n];
            const float wsm = __expf(-(float)(dx*dx + dy*dy) * (1.f/18.f)) * nv0.w;
            const float dr0 = cv0.x-nv0.x, dg0 = cv0.y-nv0.y, db0 = cv0.z-nv0.z;
            const float dr1 = cv1.x-nv1.x, dg1 = cv1.y-nv1.y, db1 = cv1.z-nv1.z;
            const float wb0 = wsm * __expf(-0.5f*(dr0*dr0+dg0*dg0+db0*db0));
            const float wb1 = wsm * __expf(-0.5f*(dr1*dr1+dg1*dg1+db1*db1));
            half2f hw = {(_Float16)wb0, (_Float16)wb1};
            unsigned uw; __builtin_memcpy(&uw, &hw, 4);
            wbW[(t >> 1) * 256 + px * 2 + (t & 1)] = uw;   // [pair][px] uint2
        }
        if (g == 4) wbW[24 * 256 + px * 2 + 1] = 0u;       // dummy tap 49
    }
    __syncthreads();

    // ---- phase 2b: per-pixel inverse norms (re-summed from LDS; no exp) ----
    float snI, bnI0, bnI1;
    {
        float sn = 0.f, bn0 = 0.f, bn1 = 0.f;
        #pragma unroll
        for (int t = 0; t < 49; ++t) {
            const unsigned uw = wbW[(t >> 1) * 256 + px * 2 + (t & 1)];
            half2f hw; __builtin_memcpy(&hw, &uw, 4);
            bn0 += (float)hw.x; bn1 += (float)hw.y;
            const int dx = t / 7 - SPAN, dy = t % 7 - SPAN;
            const int yi = ti0 + r + dx, xj = tj0 + c + dy;
            sn += (((unsigned)yi < HH) && ((unsigned)xj < WW)) ? WSPC[t] : 0.0f;
        }
        snI  = fast_rcp(sn + EPSF);
        bnI0 = fast_rcp(bn0 + EPSF);
        bnI1 = fast_rcp(bn1 + EPSF);
    }

    // ---- one-time: unaries, diag coefficients, path flag ----
    float uv0[4], uv1[4], dsv[4], dbv[4];
    #pragma unroll
    for (int i = 0; i < 4; ++i) {
        const int ch = 4*g + i;
        uv0[i] = (ch < NC) ? u[(size_t)gp * NC + ch] : 0.0f;
        uv1[i] = (ch < NC) ? u[((size_t)NPIX + gp) * NC + ch] : 0.0f;
        dsv[i] = M[960 + ku + i];
        dbv[i] = M[980 + ku + i];
    }
    const bool isdiag = (M[1000] != 0.0f);

    for (int it = 0; it < 5; ++it) {
        if (it > 0) {   // fence-free grid barrier
            __syncthreads();
            if (tid == 0) {
                __hip_atomic_fetch_add(&bar[1], 1u, __ATOMIC_RELAXED, __HIP_MEMORY_SCOPE_AGENT);
                while (__hip_atomic_load(&bar[1], __ATOMIC_RELAXED, __HIP_MEMORY_SCOPE_AGENT)
                       < (unsigned)(NBLK * it))
                    __builtin_amdgcn_s_sleep(2);
            }
            __syncthreads();
        }

        // ---- stage sm0 halo (f16); iter0 straight from u, else ping-pong ----
        const unsigned long long* gsrc = ((it & 1) ? gsmA : gsmB);  // it1<-A,it2<-B,...
        #pragma unroll
        for (int k2 = 0; k2 < 3; ++k2) {
            const int e = tid + NTHR * k2;
            if (e < NG * NHALO) {
                const int sg = e / NHALO, pos = e - sg * NHALO;
                const int hr = pos / LC, hc = pos - hr * LC;
                const int yi = ti0 - SPAN + hr, xj = tj0 - SPAN + hc;
                half4 hv = (half4)(_Float16)0.0f;
                if ((unsigned)yi < HH && (unsigned)xj < WW) {
                    const int p = yi * WW + xj;
                    if (it == 0) {
                        const float* q0 = u + (size_t)p * NC;
                        const float* q1 = u + (size_t)(NPIX + p) * NC;
                        #pragma unroll
                        for (int i = 0; i < 4; ++i) {
                            const int ch = 4*sg + i;
                            const float a = (ch < NC) ? q0[ch] : 0.0f;
                            const float d = (ch < NC) ? q1[ch] : 0.0f;
                            hv[i] = (_Float16)smx0(a, d);
                        }
                    } else {
                        const unsigned long long raw =
                            __hip_atomic_load(&gsrc[sg * NPIX + p],
                                              __ATOMIC_RELAXED, __HIP_MEMORY_SCOPE_AGENT);
                        __builtin_memcpy(&hv, &raw, 8);
                    }
                }
                smH[sg * HSTRIDE + hr * LCP + hc] = hv;
            }
        }
        __syncthreads();

        // ---- 49 taps as 24 pairs + 1: zero exp, zero masks ----
        float4v sAv = (float4v)0.0f, b0a = (float4v)0.0f, b1a = (float4v)0.0f;
        const half4* pl = smH + g * HSTRIDE;
        #pragma unroll
        for (int i = 0; i < 24; ++i) {
            const uint2 wp = wbP[i * 128 + px];
            #pragma unroll
            for (int s = 0; s < 2; ++s) {
                const int t = 2*i + s;
                const int dx = t / 7 - SPAN, dy = t % 7 - SPAN;
                half2f hw; __builtin_memcpy(&hw, s ? &wp.y : &wp.x, 4);
                const float w0 = (float)hw.x, w1 = (float)hw.y;
                const half4 v = pl[ctr + dx*LCP + dy];
                const float4v f = {(float)v[0], (float)v[1], (float)v[2], (float)v[3]};
                sAv += WSPC[t] * f;
                b0a += w0 * f;
                b1a += w1 * f;
            }
        }
        {   // tap 48 (dx=3, dy=3)
            const uint2 wp = wbP[24 * 128 + px];
            half2f hw; __builtin_memcpy(&hw, &wp.x, 4);
            const float w0 = (float)hw.x, w1 = (float)hw.y;
            const half4 v = pl[ctr + SPAN*LCP + SPAN];
            const float4v f = {(float)v[0], (float)v[1], (float)v[2], (float)v[3]};
            sAv += WSPC[48] * f;
            b0a += w0 * f;
            b1a += w1 * f;
        }

        float q0v[4], q1v[4];
        if (isdiag) {
            // ---- diag fast path (verified R9): channel-local pairwise ----
            #pragma unroll
            for (int i = 0; i < 4; ++i) {
                const float sAn = sAv[i] * snI;
                const float b0n = b0a[i] * bnI0;
                const float b1x = b1a[i] * bnI1;
                q0v[i] = uv0[i] - dsv[i]*sAn - dbv[i]*b0n;
                q1v[i] = uv1[i] - (dsv[i] + dbv[i]) + dsv[i]*sAn + dbv[i]*b1x;
            }
        } else {
            // ---- general path: cross-channel matvec via accF + s_load M ----
            __syncthreads();   // smH dead -> region A becomes accF
            #pragma unroll
            for (int i = 0; i < 4; ++i) {
                accF[(4*g + i) * NPXT + px]      = sAv[i] * snI;
                accF[(20 + 4*g + i) * NPXT + px] = b0a[i] * bnI0;
                accF[(40 + 4*g + i) * NPXT + px] = b1a[i] * bnI1;
            }
            __syncthreads();
            float t1[4] = {0,0,0,0}, t2[4] = {0,0,0,0}, t3[4] = {0,0,0,0};
            #pragma unroll
            for (int cc = 0; cc < 20; ++cc) {
                const float sv  = accF[cc * NPXT + px];
                const float b0v = accF[(20 + cc) * NPXT + px];
                const float b1v = accF[(40 + cc) * NPXT + px];
                #pragma unroll
                for (int i = 0; i < 4; ++i) {
                    const float* mk = M + (ku + i) * 48;
                    t1[i] += mk[cc] * sv;
                    t2[i] += mk[20 + cc] * b0v;
                    t3[i] += mk[20 + cc] * b1v;
                }
            }
            #pragma unroll
            for (int i = 0; i < 4; ++i) {
                const float rs = M[(ku + i) * 48 + 40];
                q0v[i] = uv0[i] - t1[i] - t2[i];
                q1v[i] = uv1[i] - rs + t1[i] + t3[i];
            }
        }

        if (it == 4) {
            #pragma unroll
            for (int i = 0; i < 4; ++i) {
                const int ch = 4*g + i;
                if (ch < NC) {
                    out[(size_t)gp * NC + ch]          = q0v[i];
                    out[((size_t)NPIX + gp) * NC + ch] = q1v[i];
                }
            }
        } else {
            half4 sh;
            #pragma unroll
            for (int i = 0; i < 4; ++i) sh[i] = (_Float16)smx0(q0v[i], q1v[i]);
            unsigned long long u64; __builtin_memcpy(&u64, &sh, 8);
            unsigned long long* gdst = ((it & 1) ? gsmB : gsmA);   // it0->A, it1->B,...
            __hip_atomic_store(&gdst[g * NPIX + gp], u64,
                               __ATOMIC_RELAXED, __HIP_MEMORY_SCOPE_AGENT);
        }
    }
}

extern "C" void kernel_launch(void* const* d_in, const int* in_sizes, int n_in,
                              void* d_out, int out_size, void* d_ws, size_t ws_size,
                              hipStream_t stream) {
    const float* u      = (const float*)d_in[0];
    const float* rgb    = (const float*)d_in[1];
    const float* sw     = (const float*)d_in[2];
    const float* bw     = (const float*)d_in[3];
    const float* compat = (const float*)d_in[4];
    float* out = (float*)d_out;

    unsigned long long* gsmA = (unsigned long long*)d_ws;              // 1,024,000 B
    unsigned long long* gsmB = (unsigned long long*)((char*)d_ws + 1024000);
    float*    M   = (float*)((char*)d_ws + 2048000);                   // 4,104 B
    unsigned* bar = (unsigned*)((char*)d_ws + 2056192);                // flag+counter

    prep_kernel<<<1, 960, 0, stream>>>(sw, bw, compat, M);
    crf_kernel<<<dim3(WW/TC, HH/TR, 1), dim3(NTHR), 0, stream>>>(
        u, rgb, M, gsmA, gsmB, bar, out);
}

// Round 11
// 128.590 us; speedup vs baseline: 4.3372x; 1.0088x over previous
//
#include <hip/hip_runtime.h>

// ConvCRF forward, MI355X — round 11: single dispatch (prep merged) + ring-only
// staging via interior self-write.
// R10 post-mortem: crf 57us (latency-exposed, VALUBusy 24%, 2.5 waves/SIMD),
// total 129.7 = crf + prep dispatch (~10) + fixed gap (~60).
// Changes:
//  - prep merged into crf prologue: M=[Ms|Mb|RS] computed redundantly per block
//    into LDS (960 entries / 640 thr), diag-detect via shared atomicAnd ->
//    one dispatch total.
//  - diag path: epilogue writes own sm0 (f16) straight into smH interior
//    (after a sync); staging then loads only the 900-entry halo RING from gsm
//    (2 rounds vs 3, ~40% fewer IF$-latency loads per iter).
// Proven pieces kept: 200-block grid, fence-free barrier (relaxed agent atomics,
// __syncthreads drains vmcnt), f16 ping-pong sm0 exchange, batch algebra
// sm1=1-sm0, diag fast path (verified R9/R10), LDS tap weights (R9 spill lesson).

typedef __attribute__((ext_vector_type(4))) _Float16 half4;
typedef __attribute__((ext_vector_type(2))) _Float16 half2f;
typedef __attribute__((ext_vector_type(4))) float float4v;

#define HH 160
#define WW 160
#define NPIX (HH*WW)
#define NC 19
#define NG 5
#define SPAN 3
#define TR 8
#define TC 16
#define NPXT 128
#define LR 14              // TR + 2*SPAN
#define LC 22              // TC + 2*SPAN
#define LCP 24             // padded halo row stride (half4 units)
#define HSTRIDE (LR*LCP)   // 336
#define NHALO (LR*LC)      // 308
#define NRING 180          // NHALO - 8*16 interior
#define NBLK 200
#define NTHR 640
#define EPSF 1e-20f
#define MAGICV 0x5EEDF00Du

// LDS: region A (30,720B) time-shared: rgbL(2x336 f4=10,752) -> smH(5x336
// h4=13,440) -> accF(60x128 f32=30,720; general path only). wbP 25x128 uint2 =
// 25,600B. Msh 960 f32 = 3,840B (persistent; general-path matvec source).
#define SZ_A    30720
#define OFF_WB  SZ_A
#define SHM_SZ  (SZ_A + 25*128*8)   // 56,320

__device__ __forceinline__ float fast_rcp(float x) { return __builtin_amdgcn_rcpf(x); }

__device__ __forceinline__ float smx0(float q0, float q1) {
    const float m  = fmaxf(q0, q1);
    const float e0 = __expf(q0 - m);
    const float e1 = __expf(q1 - m);
    return e0 * fast_rcp(e0 + e1);
}

__global__ void __launch_bounds__(NTHR) crf_kernel(
        const float* __restrict__ u,
        const float* __restrict__ rgb,
        const float* __restrict__ sw,
        const float* __restrict__ bw,
        const float* __restrict__ compat,
        unsigned long long* __restrict__ gsmA,   // ping-pong sm0 fields
        unsigned long long* __restrict__ gsmB,
        unsigned* __restrict__ bar,              // [0]=flag, [1]=counter
        float* __restrict__ out) {
    __shared__ __align__(16) char shm[SHM_SZ];
    __shared__ float Msh[960];                   // 20x48 rows [Ms|Mb|RS|pad]
    __shared__ int   diagflag;
    float4*   rgbL = (float4*)shm;               // prologue only
    half4*    smH  = (half4*)shm;                // per-iter sm0 halo (f16)
    float*    accF = (float*)shm;                // general-path epilogue
    unsigned* wbW  = (unsigned*)(shm + OFF_WB);
    const uint2* wbP = (const uint2*)(shm + OFF_WB);

    constexpr float WSPC[49] = {
        0.36787944f,0.48567179f,0.57375342f,0.60653066f,0.57375342f,0.48567179f,0.36787944f,
        0.48567179f,0.64118039f,0.75746513f,0.80073740f,0.75746513f,0.64118039f,0.48567179f,
        0.57375342f,0.75746513f,0.89483932f,0.94595947f,0.89483932f,0.75746513f,0.57375342f,
        0.60653066f,0.80073740f,0.94595947f,1.00000000f,0.94595947f,0.80073740f,0.60653066f,
        0.57375342f,0.75746513f,0.89483932f,0.94595947f,0.89483932f,0.75746513f,0.57375342f,
        0.48567179f,0.64118039f,0.75746513f,0.80073740f,0.75746513f,0.64118039f,0.48567179f,
        0.36787944f,0.48567179f,0.57375342f,0.60653066f,0.57375342f,0.48567179f,0.36787944f };

    const int tid = threadIdx.x;
    const int px  = tid & 127;
    const int g   = tid >> 7;
    const int r   = px >> 4, c = px & 15;
    const int ti0 = blockIdx.y * TR, tj0 = blockIdx.x * TC;
    const int gp  = (ti0 + r) * WW + (tj0 + c);
    const int ctr = (r + SPAN) * LCP + (c + SPAN);
    const int ku  = 4 * g;

    // ---- barrier init handshake (ws poisoned 0xAA before every launch) ----
    if ((blockIdx.x | blockIdx.y) == 0 && tid == 0) {
        __hip_atomic_store(&bar[1], 0u, __ATOMIC_RELAXED, __HIP_MEMORY_SCOPE_AGENT);
        __hip_atomic_store(&bar[0], MAGICV, __ATOMIC_RELEASE, __HIP_MEMORY_SCOPE_AGENT);
    }
    if (tid == 0) {
        diagflag = 1;
        while (__hip_atomic_load(&bar[0], __ATOMIC_ACQUIRE, __HIP_MEMORY_SCOPE_AGENT) != MAGICV)
            __builtin_amdgcn_s_sleep(2);
    }
    __syncthreads();

    // ---- phase 0: M = [compat@sw | compat@bw | RS] into LDS (per block) ----
    for (int e = tid; e < 960; e += NTHR) {
        const int k = e / 48, cc2 = e % 48;
        float acc = 0.0f;
        if (k < NC) {
            if (cc2 < NC) {
                for (int j = 0; j < NC; ++j) acc += compat[k*NC + j] * sw[j*NC + cc2];
            } else if (cc2 >= 20 && cc2 < 20 + NC) {
                const int cb = cc2 - 20;
                for (int j = 0; j < NC; ++j) acc += compat[k*NC + j] * bw[j*NC + cb];
            } else if (cc2 == 40) {
                for (int j = 0; j < NC; ++j) {
                    float rs = 0.0f;
                    for (int cb = 0; cb < NC; ++cb) rs += sw[j*NC + cb] + bw[j*NC + cb];
                    acc += compat[k*NC + j] * rs;
                }
            }
        }
        Msh[e] = acc;
        bool off = false;
        if (k < NC) {
            if (cc2 < NC && cc2 != k && acc != 0.0f) off = true;
            if (cc2 >= 20 && cc2 < 20 + NC && (cc2 - 20) != k && acc != 0.0f) off = true;
        }
        if (off) atomicAnd(&diagflag, 0);
    }
    __syncthreads();

    // diag coefficients (rows >= NC are zero by construction)
    float dsv[4], dbv[4];
    #pragma unroll
    for (int i = 0; i < 4; ++i) {
        dsv[i] = Msh[(ku + i) * 48 + (ku + i)];
        dbv[i] = Msh[(ku + i) * 48 + 20 + (ku + i)];
    }
    const bool isdiag = (diagflag != 0);

    // ---- phase 1: rgb halo, both batches (scaled 1/160, .w = validity) ----
    for (int e = tid; e < 2 * NHALO; e += NTHR) {
        const int bb = e / NHALO, pos = e % NHALO;
        const int hr = pos / LC, hc = pos % LC;
        const int yi = ti0 - SPAN + hr, xj = tj0 - SPAN + hc;
        float4 rv = make_float4(0.f, 0.f, 0.f, 0.f);
        if ((unsigned)yi < HH && (unsigned)xj < WW) {
            const float* p = rgb + ((size_t)(bb * NPIX) + yi * WW + xj) * 3;
            rv = make_float4(p[0]*(1.f/160.f), p[1]*(1.f/160.f), p[2]*(1.f/160.f), 1.f);
        }
        rgbL[(bb ? HSTRIDE : 0) + hr * LCP + hc] = rv;
    }
    __syncthreads();

    // ---- phase 2a: bilateral weights (tap-subset per group) -> LDS pairs ----
    {
        const float4 cv0 = rgbL[ctr];
        const float4 cv1 = rgbL[HSTRIDE + ctr];
        const int tapb = g * 10;
        const int ntap = (g == 4) ? 9 : 10;
        for (int i = 0; i < ntap; ++i) {
            const int t = tapb + i;
            const int dx = t / 7 - SPAN, dy = t % 7 - SPAN;
            const int n = ctr + dx * LCP + dy;
            const float4 nv0 = rgbL[n];
            const float4 nv1 = rgbL[HSTRIDE + n];
            const float wsm = __expf(-(float)(dx*dx + dy*dy) * (1.f/18.f)) * nv0.w;
            const float dr0 = cv0.x-nv0.x, dg0 = cv0.y-nv0.y, db0 = cv0.z-nv0.z;
            const float dr1 = cv1.x-nv1.x, dg1 = cv1.y-nv1.y, db1 = cv1.z-nv1.z;
            const float wb0 = wsm * __expf(-0.5f*(dr0*dr0+dg0*dg0+db0*db0));
            const float wb1 = wsm * __expf(-0.5f*(dr1*dr1+dg1*dg1+db1*db1));
            half2f hw = {(_Float16)wb0, (_Float16)wb1};
            unsigned uw; __builtin_memcpy(&uw, &hw, 4);
            wbW[(t >> 1) * 256 + px * 2 + (t & 1)] = uw;
        }
        if (g == 4) wbW[24 * 256 + px * 2 + 1] = 0u;   // dummy tap 49
    }
    __syncthreads();

    // ---- phase 2b: per-pixel inverse norms (re-summed from LDS; no exp) ----
    float snI, bnI0, bnI1;
    {
        float sn = 0.f, bn0 = 0.f, bn1 = 0.f;
        #pragma unroll
        for (int t = 0; t < 49; ++t) {
            const unsigned uw = wbW[(t >> 1) * 256 + px * 2 + (t & 1)];
            half2f hw; __builtin_memcpy(&hw, &uw, 4);
            bn0 += (float)hw.x; bn1 += (float)hw.y;
            const int dx = t / 7 - SPAN, dy = t % 7 - SPAN;
            const int yi = ti0 + r + dx, xj = tj0 + c + dy;
            sn += (((unsigned)yi < HH) && ((unsigned)xj < WW)) ? WSPC[t] : 0.0f;
        }
        snI  = fast_rcp(sn + EPSF);
        bnI0 = fast_rcp(bn0 + EPSF);
        bnI1 = fast_rcp(bn1 + EPSF);
    }

    // ---- one-time: own unaries ----
    float uv0[4], uv1[4];
    #pragma unroll
    for (int i = 0; i < 4; ++i) {
        const int ch = 4*g + i;
        uv0[i] = (ch < NC) ? u[(size_t)gp * NC + ch] : 0.0f;
        uv1[i] = (ch < NC) ? u[((size_t)NPIX + gp) * NC + ch] : 0.0f;
    }

    for (int it = 0; it < 5; ++it) {
        if (it > 0) {   // fence-free grid barrier
            __syncthreads();
            if (tid == 0) {
                __hip_atomic_fetch_add(&bar[1], 1u, __ATOMIC_RELAXED, __HIP_MEMORY_SCOPE_AGENT);
                while (__hip_atomic_load(&bar[1], __ATOMIC_RELAXED, __HIP_MEMORY_SCOPE_AGENT)
                       < (unsigned)(NBLK * it))
                    __builtin_amdgcn_s_sleep(2);
            }
            __syncthreads();
        }

        // ---- stage sm0 halo ----
        const unsigned long long* gsrc = ((it & 1) ? gsmA : gsmB);
        if (it == 0) {
            // full halo straight from u (includes interior)
            #pragma unroll
            for (int k2 = 0; k2 < 3; ++k2) {
                const int e = tid + NTHR * k2;
                if (e < NG * NHALO) {
                    const int sg = e / NHALO, pos = e - sg * NHALO;
                    const int hr = pos / LC, hc = pos - hr * LC;
                    const int yi = ti0 - SPAN + hr, xj = tj0 - SPAN + hc;
                    half4 hv = (half4)(_Float16)0.0f;
                    if ((unsigned)yi < HH && (unsigned)xj < WW) {
                        const int p = yi * WW + xj;
                        const float* q0 = u + (size_t)p * NC;
                        const float* q1 = u + (size_t)(NPIX + p) * NC;
                        #pragma unroll
                        for (int i = 0; i < 4; ++i) {
                            const int ch = 4*sg + i;
                            const float a = (ch < NC) ? q0[ch] : 0.0f;
                            const float d = (ch < NC) ? q1[ch] : 0.0f;
                            hv[i] = (_Float16)smx0(a, d);
                        }
                    }
                    smH[sg * HSTRIDE + hr * LCP + hc] = hv;
                }
            }
        } else if (isdiag) {
            // ring only (interior was self-written last epilogue)
            #pragma unroll
            for (int k2 = 0; k2 < 2; ++k2) {
                const int e = tid + NTHR * k2;
                if (e < NG * NRING) {
                    const int sg = e / NRING, re = e - sg * NRING;
                    int hr, hc;
                    if (re < 66)        { hr = re / 22;          hc = re % 22; }
                    else if (re < 132)  { const int t2 = re - 66;  hr = 11 + t2 / 22; hc = t2 % 22; }
                    else                { const int t2 = re - 132; hr = 3 + t2 / 6;
                                          const int s = t2 % 6;    hc = (s < 3) ? s : s + 16; }
                    const int yi = ti0 - SPAN + hr, xj = tj0 - SPAN + hc;
                    half4 hv = (half4)(_Float16)0.0f;
                    if ((unsigned)yi < HH && (unsigned)xj < WW) {
                        const unsigned long long raw =
                            __hip_atomic_load(&gsrc[sg * NPIX + yi * WW + xj],
                                              __ATOMIC_RELAXED, __HIP_MEMORY_SCOPE_AGENT);
                        __builtin_memcpy(&hv, &raw, 8);
                    }
                    smH[sg * HSTRIDE + hr * LCP + hc] = hv;
                }
            }
        } else {
            // general path: full halo from gsm (accF aliasing kills self-write)
            #pragma unroll
            for (int k2 = 0; k2 < 3; ++k2) {
                const int e = tid + NTHR * k2;
                if (e < NG * NHALO) {
                    const int sg = e / NHALO, pos = e - sg * NHALO;
                    const int hr = pos / LC, hc = pos - hr * LC;
                    const int yi = ti0 - SPAN + hr, xj = tj0 - SPAN + hc;
                    half4 hv = (half4)(_Float16)0.0f;
                    if ((unsigned)yi < HH && (unsigned)xj < WW) {
                        const unsigned long long raw =
                            __hip_atomic_load(&gsrc[sg * NPIX + yi * WW + xj],
                                              __ATOMIC_RELAXED, __HIP_MEMORY_SCOPE_AGENT);
                        __builtin_memcpy(&hv, &raw, 8);
                    }
                    smH[sg * HSTRIDE + hr * LCP + hc] = hv;
                }
            }
        }
        __syncthreads();

        // ---- 49 taps as 24 pairs + 1: zero exp, zero masks ----
        float4v sAv = (float4v)0.0f, b0a = (float4v)0.0f, b1a = (float4v)0.0f;
        const half4* pl = smH + g * HSTRIDE;
        #pragma unroll
        for (int i = 0; i < 24; ++i) {
            const uint2 wp = wbP[i * 128 + px];
            #pragma unroll
            for (int s = 0; s < 2; ++s) {
                const int t = 2*i + s;
                const int dx = t / 7 - SPAN, dy = t % 7 - SPAN;
                half2f hw; __builtin_memcpy(&hw, s ? &wp.y : &wp.x, 4);
                const float w0 = (float)hw.x, w1 = (float)hw.y;
                const half4 v = pl[ctr + dx*LCP + dy];
                const float4v f = {(float)v[0], (float)v[1], (float)v[2], (float)v[3]};
                sAv += WSPC[t] * f;
                b0a += w0 * f;
                b1a += w1 * f;
            }
        }
        {   // tap 48 (dx=3, dy=3)
            const uint2 wp = wbP[24 * 128 + px];
            half2f hw; __builtin_memcpy(&hw, &wp.x, 4);
            const float w0 = (float)hw.x, w1 = (float)hw.y;
            const half4 v = pl[ctr + SPAN*LCP + SPAN];
            const float4v f = {(float)v[0], (float)v[1], (float)v[2], (float)v[3]};
            sAv += WSPC[48] * f;
            b0a += w0 * f;
            b1a += w1 * f;
        }

        if (isdiag) {
            // ---- diag fast path (verified R9/R10) ----
            float q0v[4], q1v[4];
            #pragma unroll
            for (int i = 0; i < 4; ++i) {
                const float sAn = sAv[i] * snI;
                const float b0n = b0a[i] * bnI0;
                const float b1x = b1a[i] * bnI1;
                q0v[i] = uv0[i] - dsv[i]*sAn - dbv[i]*b0n;
                q1v[i] = uv1[i] - (dsv[i] + dbv[i]) + dsv[i]*sAn + dbv[i]*b1x;
            }
            if (it == 4) {
                #pragma unroll
                for (int i = 0; i < 4; ++i) {
                    const int ch = 4*g + i;
                    if (ch < NC) {
                        out[(size_t)gp * NC + ch]          = q0v[i];
                        out[((size_t)NPIX + gp) * NC + ch] = q1v[i];
                    }
                }
            } else {
                half4 sh;
                #pragma unroll
                for (int i = 0; i < 4; ++i) sh[i] = (_Float16)smx0(q0v[i], q1v[i]);
                __syncthreads();               // all tap reads of smH complete
                smH[g * HSTRIDE + ctr] = sh;   // interior self-write for next iter
                unsigned long long u64; __builtin_memcpy(&u64, &sh, 8);
                unsigned long long* gdst = ((it & 1) ? gsmB : gsmA);
                __hip_atomic_store(&gdst[g * NPIX + gp], u64,
                                   __ATOMIC_RELAXED, __HIP_MEMORY_SCOPE_AGENT);
            }
        } else {
            // ---- general path: cross-channel matvec via accF + LDS M ----
            float q0v[4], q1v[4];
            __syncthreads();   // smH dead -> region A becomes accF
            #pragma unroll
            for (int i = 0; i < 4; ++i) {
                accF[(4*g + i) * NPXT + px]      = sAv[i] * snI;
                accF[(20 + 4*g + i) * NPXT + px] = b0a[i] * bnI0;
                accF[(40 + 4*g + i) * NPXT + px] = b1a[i] * bnI1;
            }
            __syncthreads();
            float t1[4] = {0,0,0,0}, t2[4] = {0,0,0,0}, t3[4] = {0,0,0,0};
            #pragma unroll
            for (int cc = 0; cc < 20; ++cc) {
                const float sv  = accF[cc * NPXT + px];
                const float b0v = accF[(20 + cc) * NPXT + px];
                const float b1v = accF[(40 + cc) * NPXT + px];
                #pragma unroll
                for (int i = 0; i < 4; ++i) {
                    const float* mk = Msh + (ku + i) * 48;
                    t1[i] += mk[cc] * sv;
                    t2[i] += mk[20 + cc] * b0v;
                    t3[i] += mk[20 + cc] * b1v;
                }
            }
            #pragma unroll
            for (int i = 0; i < 4; ++i) {
                const float rs = Msh[(ku + i) * 48 + 40];
                q0v[i] = uv0[i] - t1[i] - t2[i];
                q1v[i] = uv1[i] - rs + t1[i] + t3[i];
            }
            if (it == 4) {
                #pragma unroll
                for (int i = 0; i < 4; ++i) {
                    const int ch = 4*g + i;
                    if (ch < NC) {
                        out[(size_t)gp * NC + ch]          = q0v[i];
                        out[((size_t)NPIX + gp) * NC + ch] = q1v[i];
                    }
                }
            } else {
                half4 sh;
                #pragma unroll
                for (int i = 0; i < 4; ++i) sh[i] = (_Float16)smx0(q0v[i], q1v[i]);
                unsigned long long u64; __builtin_memcpy(&u64, &sh, 8);
                unsigned long long* gdst = ((it & 1) ? gsmB : gsmA);
                __hip_atomic_store(&gdst[g * NPIX + gp], u64,
                                   __ATOMIC_RELAXED, __HIP_MEMORY_SCOPE_AGENT);
            }
        }
    }
}

extern "C" void kernel_launch(void* const* d_in, const int* in_sizes, int n_in,
                              void* d_out, int out_size, void* d_ws, size_t ws_size,
                              hipStream_t stream) {
    const float* u      = (const float*)d_in[0];
    const float* rgb    = (const float*)d_in[1];
    const float* sw     = (const float*)d_in[2];
    const float* bw     = (const float*)d_in[3];
    const float* compat = (const float*)d_in[4];
    float* out = (float*)d_out;

    unsigned long long* gsmA = (unsigned long long*)d_ws;              // 1,024,000 B
    unsigned long long* gsmB = (unsigned long long*)((char*)d_ws + 1024000);
    unsigned* bar = (unsigned*)((char*)d_ws + 2048000);                // flag+counter

    crf_kernel<<<dim3(WW/TC, HH/TR, 1), dim3(NTHR), 0, stream>>>(
        u, rgb, sw, bw, compat, gsmA, gsmB, bar, out);
}

// Round 12
// 118.535 us; speedup vs baseline: 4.7051x; 1.0848x over previous
//
#include <hip/hip_runtime.h>

// ConvCRF forward, MI355X — round 12: R11 structure, phase-0 fixed to O(19)/entry.
// R11 post-mortem: crf 57->74us after merging prep. Root cause: RS column
// computed with a nested O(19^2) global-load loop (722 L2-latency loads on 20
// threads; every block's syncthreads waits on them). Fix: rowsum[j] precomputed
// once into LDS (one pass over sw+bw), RS[k] = sum_j compat[k,j]*rowsum[j].
// Ring staging + interior self-write kept from R11 (neutral-to-positive; if crf
// stays high this round they become the isolated suspect).
// Proven pieces: 200-block grid, fence-free barrier (relaxed agent atomics,
// __syncthreads drains vmcnt), f16 ping-pong sm0 exchange, batch algebra
// sm1=1-sm0, diag fast path, LDS tap weights (R9 spill lesson).

typedef __attribute__((ext_vector_type(4))) _Float16 half4;
typedef __attribute__((ext_vector_type(2))) _Float16 half2f;
typedef __attribute__((ext_vector_type(4))) float float4v;

#define HH 160
#define WW 160
#define NPIX (HH*WW)
#define NC 19
#define NG 5
#define SPAN 3
#define TR 8
#define TC 16
#define NPXT 128
#define LR 14              // TR + 2*SPAN
#define LC 22              // TC + 2*SPAN
#define LCP 24             // padded halo row stride (half4 units)
#define HSTRIDE (LR*LCP)   // 336
#define NHALO (LR*LC)      // 308
#define NRING 180          // NHALO - 8*16 interior
#define NBLK 200
#define NTHR 640
#define EPSF 1e-20f
#define MAGICV 0x5EEDF00Du

#define SZ_A    30720
#define OFF_WB  SZ_A
#define SHM_SZ  (SZ_A + 25*128*8)   // 56,320

__device__ __forceinline__ float fast_rcp(float x) { return __builtin_amdgcn_rcpf(x); }

__device__ __forceinline__ float smx0(float q0, float q1) {
    const float m  = fmaxf(q0, q1);
    const float e0 = __expf(q0 - m);
    const float e1 = __expf(q1 - m);
    return e0 * fast_rcp(e0 + e1);
}

__global__ void __launch_bounds__(NTHR) crf_kernel(
        const float* __restrict__ u,
        const float* __restrict__ rgb,
        const float* __restrict__ sw,
        const float* __restrict__ bw,
        const float* __restrict__ compat,
        unsigned long long* __restrict__ gsmA,   // ping-pong sm0 fields
        unsigned long long* __restrict__ gsmB,
        unsigned* __restrict__ bar,              // [0]=flag, [1]=counter
        float* __restrict__ out) {
    __shared__ __align__(16) char shm[SHM_SZ];
    __shared__ float Msh[960];                   // 20x48 rows [Ms|Mb|RS|pad]
    __shared__ float rowsum[NC];
    __shared__ int   diagflag;
    float4*   rgbL = (float4*)shm;               // prologue only
    half4*    smH  = (half4*)shm;                // per-iter sm0 halo (f16)
    float*    accF = (float*)shm;                // general-path epilogue
    unsigned* wbW  = (unsigned*)(shm + OFF_WB);
    const uint2* wbP = (const uint2*)(shm + OFF_WB);

    constexpr float WSPC[49] = {
        0.36787944f,0.48567179f,0.57375342f,0.60653066f,0.57375342f,0.48567179f,0.36787944f,
        0.48567179f,0.64118039f,0.75746513f,0.80073740f,0.75746513f,0.64118039f,0.48567179f,
        0.57375342f,0.75746513f,0.89483932f,0.94595947f,0.89483932f,0.75746513f,0.57375342f,
        0.60653066f,0.80073740f,0.94595947f,1.00000000f,0.94595947f,0.80073740f,0.60653066f,
        0.57375342f,0.75746513f,0.89483932f,0.94595947f,0.89483932f,0.75746513f,0.57375342f,
        0.48567179f,0.64118039f,0.75746513f,0.80073740f,0.75746513f,0.64118039f,0.48567179f,
        0.36787944f,0.48567179f,0.57375342f,0.60653066f,0.57375342f,0.48567179f,0.36787944f };

    const int tid = threadIdx.x;
    const int px  = tid & 127;
    const int g   = tid >> 7;
    const int r   = px >> 4, c = px & 15;
    const int ti0 = blockIdx.y * TR, tj0 = blockIdx.x * TC;
    const int gp  = (ti0 + r) * WW + (tj0 + c);
    const int ctr = (r + SPAN) * LCP + (c + SPAN);
    const int ku  = 4 * g;

    // ---- barrier init handshake (ws poisoned 0xAA before every launch) ----
    if ((blockIdx.x | blockIdx.y) == 0 && tid == 0) {
        __hip_atomic_store(&bar[1], 0u, __ATOMIC_RELAXED, __HIP_MEMORY_SCOPE_AGENT);
        __hip_atomic_store(&bar[0], MAGICV, __ATOMIC_RELEASE, __HIP_MEMORY_SCOPE_AGENT);
    }
    if (tid == 0) {
        diagflag = 1;
        while (__hip_atomic_load(&bar[0], __ATOMIC_ACQUIRE, __HIP_MEMORY_SCOPE_AGENT) != MAGICV)
            __builtin_amdgcn_s_sleep(2);
    }
    // rowsum[j] = sum_c (sw[j,c] + bw[j,c])  — one O(19) pass, 19 threads
    if (tid < NC) {
        float rs = 0.0f;
        for (int cb = 0; cb < NC; ++cb) rs += sw[tid*NC + cb] + bw[tid*NC + cb];
        rowsum[tid] = rs;
    }
    __syncthreads();

    // ---- phase 0: M = [compat@sw | compat@bw | RS] into LDS, O(19)/entry ----
    for (int e = tid; e < 960; e += NTHR) {
        const int k = e / 48, cc2 = e % 48;
        float acc = 0.0f;
        if (k < NC) {
            if (cc2 < NC) {
                for (int j = 0; j < NC; ++j) acc += compat[k*NC + j] * sw[j*NC + cc2];
            } else if (cc2 >= 20 && cc2 < 20 + NC) {
                const int cb = cc2 - 20;
                for (int j = 0; j < NC; ++j) acc += compat[k*NC + j] * bw[j*NC + cb];
            } else if (cc2 == 40) {
                for (int j = 0; j < NC; ++j) acc += compat[k*NC + j] * rowsum[j];
            }
        }
        Msh[e] = acc;
        bool off = false;
        if (k < NC) {
            if (cc2 < NC && cc2 != k && acc != 0.0f) off = true;
            if (cc2 >= 20 && cc2 < 20 + NC && (cc2 - 20) != k && acc != 0.0f) off = true;
        }
        if (off) atomicAnd(&diagflag, 0);
    }
    __syncthreads();

    // diag coefficients (rows >= NC are zero by construction)
    float dsv[4], dbv[4];
    #pragma unroll
    for (int i = 0; i < 4; ++i) {
        dsv[i] = Msh[(ku + i) * 48 + (ku + i)];
        dbv[i] = Msh[(ku + i) * 48 + 20 + (ku + i)];
    }
    const bool isdiag = (diagflag != 0);

    // ---- phase 1: rgb halo, both batches (scaled 1/160, .w = validity) ----
    for (int e = tid; e < 2 * NHALO; e += NTHR) {
        const int bb = e / NHALO, pos = e % NHALO;
        const int hr = pos / LC, hc = pos % LC;
        const int yi = ti0 - SPAN + hr, xj = tj0 - SPAN + hc;
        float4 rv = make_float4(0.f, 0.f, 0.f, 0.f);
        if ((unsigned)yi < HH && (unsigned)xj < WW) {
            const float* p = rgb + ((size_t)(bb * NPIX) + yi * WW + xj) * 3;
            rv = make_float4(p[0]*(1.f/160.f), p[1]*(1.f/160.f), p[2]*(1.f/160.f), 1.f);
        }
        rgbL[(bb ? HSTRIDE : 0) + hr * LCP + hc] = rv;
    }
    __syncthreads();

    // ---- phase 2a: bilateral weights (tap-subset per group) -> LDS pairs ----
    {
        const float4 cv0 = rgbL[ctr];
        const float4 cv1 = rgbL[HSTRIDE + ctr];
        const int tapb = g * 10;
        const int ntap = (g == 4) ? 9 : 10;
        for (int i = 0; i < ntap; ++i) {
            const int t = tapb + i;
            const int dx = t / 7 - SPAN, dy = t % 7 - SPAN;
            const int n = ctr + dx * LCP + dy;
            const float4 nv0 = rgbL[n];
            const float4 nv1 = rgbL[HSTRIDE + n];
            const float wsm = __expf(-(float)(dx*dx + dy*dy) * (1.f/18.f)) * nv0.w;
            const float dr0 = cv0.x-nv0.x, dg0 = cv0.y-nv0.y, db0 = cv0.z-nv0.z;
            const float dr1 = cv1.x-nv1.x, dg1 = cv1.y-nv1.y, db1 = cv1.z-nv1.z;
            const float wb0 = wsm * __expf(-0.5f*(dr0*dr0+dg0*dg0+db0*db0));
            const float wb1 = wsm * __expf(-0.5f*(dr1*dr1+dg1*dg1+db1*db1));
            half2f hw = {(_Float16)wb0, (_Float16)wb1};
            unsigned uw; __builtin_memcpy(&uw, &hw, 4);
            wbW[(t >> 1) * 256 + px * 2 + (t & 1)] = uw;
        }
        if (g == 4) wbW[24 * 256 + px * 2 + 1] = 0u;   // dummy tap 49
    }
    __syncthreads();

    // ---- phase 2b: per-pixel inverse norms (re-summed from LDS; no exp) ----
    float snI, bnI0, bnI1;
    {
        float sn = 0.f, bn0 = 0.f, bn1 = 0.f;
        #pragma unroll
        for (int t = 0; t < 49; ++t) {
            const unsigned uw = wbW[(t >> 1) * 256 + px * 2 + (t & 1)];
            half2f hw; __builtin_memcpy(&hw, &uw, 4);
            bn0 += (float)hw.x; bn1 += (float)hw.y;
            const int dx = t / 7 - SPAN, dy = t % 7 - SPAN;
            const int yi = ti0 + r + dx, xj = tj0 + c + dy;
            sn += (((unsigned)yi < HH) && ((unsigned)xj < WW)) ? WSPC[t] : 0.0f;
        }
        snI  = fast_rcp(sn + EPSF);
        bnI0 = fast_rcp(bn0 + EPSF);
        bnI1 = fast_rcp(bn1 + EPSF);
    }

    // ---- one-time: own unaries ----
    float uv0[4], uv1[4];
    #pragma unroll
    for (int i = 0; i < 4; ++i) {
        const int ch = 4*g + i;
        uv0[i] = (ch < NC) ? u[(size_t)gp * NC + ch] : 0.0f;
        uv1[i] = (ch < NC) ? u[((size_t)NPIX + gp) * NC + ch] : 0.0f;
    }

    for (int it = 0; it < 5; ++it) {
        if (it > 0) {   // fence-free grid barrier
            __syncthreads();
            if (tid == 0) {
                __hip_atomic_fetch_add(&bar[1], 1u, __ATOMIC_RELAXED, __HIP_MEMORY_SCOPE_AGENT);
                while (__hip_atomic_load(&bar[1], __ATOMIC_RELAXED, __HIP_MEMORY_SCOPE_AGENT)
                       < (unsigned)(NBLK * it))
                    __builtin_amdgcn_s_sleep(2);
            }
            __syncthreads();
        }

        // ---- stage sm0 halo ----
        const unsigned long long* gsrc = ((it & 1) ? gsmA : gsmB);
        if (it == 0) {
            #pragma unroll
            for (int k2 = 0; k2 < 3; ++k2) {
                const int e = tid + NTHR * k2;
                if (e < NG * NHALO) {
                    const int sg = e / NHALO, pos = e - sg * NHALO;
                    const int hr = pos / LC, hc = pos - hr * LC;
                    const int yi = ti0 - SPAN + hr, xj = tj0 - SPAN + hc;
                    half4 hv = (half4)(_Float16)0.0f;
                    if ((unsigned)yi < HH && (unsigned)xj < WW) {
                        const int p = yi * WW + xj;
                        const float* q0 = u + (size_t)p * NC;
                        const float* q1 = u + (size_t)(NPIX + p) * NC;
                        #pragma unroll
                        for (int i = 0; i < 4; ++i) {
                            const int ch = 4*sg + i;
                            const float a = (ch < NC) ? q0[ch] : 0.0f;
                            const float d = (ch < NC) ? q1[ch] : 0.0f;
                            hv[i] = (_Float16)smx0(a, d);
                        }
                    }
                    smH[sg * HSTRIDE + hr * LCP + hc] = hv;
                }
            }
        } else if (isdiag) {
            // ring only (interior was self-written last epilogue)
            #pragma unroll
            for (int k2 = 0; k2 < 2; ++k2) {
                const int e = tid + NTHR * k2;
                if (e < NG * NRING) {
                    const int sg = e / NRING, re = e - sg * NRING;
                    int hr, hc;
                    if (re < 66)        { hr = re / 22;          hc = re % 22; }
                    else if (re < 132)  { const int t2 = re - 66;  hr = 11 + t2 / 22; hc = t2 % 22; }
                    else                { const int t2 = re - 132; hr = 3 + t2 / 6;
                                          const int s = t2 % 6;    hc = (s < 3) ? s : s + 16; }
                    const int yi = ti0 - SPAN + hr, xj = tj0 - SPAN + hc;
                    half4 hv = (half4)(_Float16)0.0f;
                    if ((unsigned)yi < HH && (unsigned)xj < WW) {
                        const unsigned long long raw =
                            __hip_atomic_load(&gsrc[sg * NPIX + yi * WW + xj],
                                              __ATOMIC_RELAXED, __HIP_MEMORY_SCOPE_AGENT);
                        __builtin_memcpy(&hv, &raw, 8);
                    }
                    smH[sg * HSTRIDE + hr * LCP + hc] = hv;
                }
            }
        } else {
            #pragma unroll
            for (int k2 = 0; k2 < 3; ++k2) {
                const int e = tid + NTHR * k2;
                if (e < NG * NHALO) {
                    const int sg = e / NHALO, pos = e - sg * NHALO;
                    const int hr = pos / LC, hc = pos - hr * LC;
                    const int yi = ti0 - SPAN + hr, xj = tj0 - SPAN + hc;
                    half4 hv = (half4)(_Float16)0.0f;
                    if ((unsigned)yi < HH && (unsigned)xj < WW) {
                        const unsigned long long raw =
                            __hip_atomic_load(&gsrc[sg * NPIX + yi * WW + xj],
                                              __ATOMIC_RELAXED, __HIP_MEMORY_SCOPE_AGENT);
                        __builtin_memcpy(&hv, &raw, 8);
                    }
                    smH[sg * HSTRIDE + hr * LCP + hc] = hv;
                }
            }
        }
        __syncthreads();

        // ---- 49 taps as 24 pairs + 1: zero exp, zero masks ----
        float4v sAv = (float4v)0.0f, b0a = (float4v)0.0f, b1a = (float4v)0.0f;
        const half4* pl = smH + g * HSTRIDE;
        #pragma unroll
        for (int i = 0; i < 24; ++i) {
            const uint2 wp = wbP[i * 128 + px];
            #pragma unroll
            for (int s = 0; s < 2; ++s) {
                const int t = 2*i + s;
                const int dx = t / 7 - SPAN, dy = t % 7 - SPAN;
                half2f hw; __builtin_memcpy(&hw, s ? &wp.y : &wp.x, 4);
                const float w0 = (float)hw.x, w1 = (float)hw.y;
                const half4 v = pl[ctr + dx*LCP + dy];
                const float4v f = {(float)v[0], (float)v[1], (float)v[2], (float)v[3]};
                sAv += WSPC[t] * f;
                b0a += w0 * f;
                b1a += w1 * f;
            }
        }
        {   // tap 48 (dx=3, dy=3)
            const uint2 wp = wbP[24 * 128 + px];
            half2f hw; __builtin_memcpy(&hw, &wp.x, 4);
            const float w0 = (float)hw.x, w1 = (float)hw.y;
            const half4 v = pl[ctr + SPAN*LCP + SPAN];
            const float4v f = {(float)v[0], (float)v[1], (float)v[2], (float)v[3]};
            sAv += WSPC[48] * f;
            b0a += w0 * f;
            b1a += w1 * f;
        }

        if (isdiag) {
            // ---- diag fast path (verified R9/R10/R11) ----
            float q0v[4], q1v[4];
            #pragma unroll
            for (int i = 0; i < 4; ++i) {
                const float sAn = sAv[i] * snI;
                const float b0n = b0a[i] * bnI0;
                const float b1x = b1a[i] * bnI1;
                q0v[i] = uv0[i] - dsv[i]*sAn - dbv[i]*b0n;
                q1v[i] = uv1[i] - (dsv[i] + dbv[i]) + dsv[i]*sAn + dbv[i]*b1x;
            }
            if (it == 4) {
                #pragma unroll
                for (int i = 0; i < 4; ++i) {
                    const int ch = 4*g + i;
                    if (ch < NC) {
                        out[(size_t)gp * NC + ch]          = q0v[i];
                        out[((size_t)NPIX + gp) * NC + ch] = q1v[i];
                    }
                }
            } else {
                half4 sh;
                #pragma unroll
                for (int i = 0; i < 4; ++i) sh[i] = (_Float16)smx0(q0v[i], q1v[i]);
                __syncthreads();               // all tap reads of smH complete
                smH[g * HSTRIDE + ctr] = sh;   // interior self-write for next iter
                unsigned long long u64; __builtin_memcpy(&u64, &sh, 8);
                unsigned long long* gdst = ((it & 1) ? gsmB : gsmA);
                __hip_atomic_store(&gdst[g * NPIX + gp], u64,
                                   __ATOMIC_RELAXED, __HIP_MEMORY_SCOPE_AGENT);
            }
        } else {
            // ---- general path: cross-channel matvec via accF + LDS M ----
            float q0v[4], q1v[4];
            __syncthreads();   // smH dead -> region A becomes accF
            #pragma unroll
            for (int i = 0; i < 4; ++i) {
                accF[(4*g + i) * NPXT + px]      = sAv[i] * snI;
                accF[(20 + 4*g + i) * NPXT + px] = b0a[i] * bnI0;
                accF[(40 + 4*g + i) * NPXT + px] = b1a[i] * bnI1;
            }
            __syncthreads();
            float t1[4] = {0,0,0,0}, t2[4] = {0,0,0,0}, t3[4] = {0,0,0,0};
            #pragma unroll
            for (int cc = 0; cc < 20; ++cc) {
                const float sv  = accF[cc * NPXT + px];
                const float b0v = accF[(20 + cc) * NPXT + px];
                const float b1v = accF[(40 + cc) * NPXT + px];
                #pragma unroll
                for (int i = 0; i < 4; ++i) {
                    const float* mk = Msh + (ku + i) * 48;
                    t1[i] += mk[cc] * sv;
                    t2[i] += mk[20 + cc] * b0v;
                    t3[i] += mk[20 + cc] * b1v;
                }
            }
            #pragma unroll
            for (int i = 0; i < 4; ++i) {
                const float rs = Msh[(ku + i) * 48 + 40];
                q0v[i] = uv0[i] - t1[i] - t2[i];
                q1v[i] = uv1[i] - rs + t1[i] + t3[i];
            }
            if (it == 4) {
                #pragma unroll
                for (int i = 0; i < 4; ++i) {
                    const int ch = 4*g + i;
                    if (ch < NC) {
                        out[(size_t)gp * NC + ch]          = q0v[i];
                        out[((size_t)NPIX + gp) * NC + ch] = q1v[i];
                    }
                }
            } else {
                half4 sh;
                #pragma unroll
                for (int i = 0; i < 4; ++i) sh[i] = (_Float16)smx0(q0v[i], q1v[i]);
                unsigned long long u64; __builtin_memcpy(&u64, &sh, 8);
                unsigned long long* gdst = ((it & 1) ? gsmB : gsmA);
                __hip_atomic_store(&gdst[g * NPIX + gp], u64,
                                   __ATOMIC_RELAXED, __HIP_MEMORY_SCOPE_AGENT);
            }
        }
    }
}

extern "C" void kernel_launch(void* const* d_in, const int* in_sizes, int n_in,
                              void* d_out, int out_size, void* d_ws, size_t ws_size,
                              hipStream_t stream) {
    const float* u      = (const float*)d_in[0];
    const float* rgb    = (const float*)d_in[1];
    const float* sw     = (const float*)d_in[2];
    const float* bw     = (const float*)d_in[3];
    const float* compat = (const float*)d_in[4];
    float* out = (float*)d_out;

    unsigned long long* gsmA = (unsigned long long*)d_ws;              // 1,024,000 B
    unsigned long long* gsmB = (unsigned long long*)((char*)d_ws + 1024000);
    unsigned* bar = (unsigned*)((char*)d_ws + 2048000);                // flag+counter

    crf_kernel<<<dim3(WW/TC, HH/TR, 1), dim3(NTHR), 0, stream>>>(
        u, rgb, sw, bw, compat, gsmA, gsmB, bar, out);
}

// Round 13
// 110.770 us; speedup vs baseline: 5.0350x; 1.0701x over previous
//
#include <hip/hip_runtime.h>

// ConvCRF forward, MI355X — round 13: R12 + two-level distributed grid barrier.
// R12 post-mortem: crf 63.6us; ~12us/iter vs ~3us tap work. Arithmetic: 200
// atomicAdd RMWs to ONE IF$ line serialize (~100cyc each) = ~8us/barrier x4 =
// the unexplained budget. Fix (only change this round):
//  - 8 cache-line-separated counters, block b adds to counter[b&7] (25 RMWs per
//    line, parallel across lines ~1us).
//  - block 0 spin-sums counters to 200*it, then stores a release epoch; other
//    blocks spin on the release word with plain relaxed loads (no RMW serialization).
// Visibility reasoning identical to proven R8-R12 protocol: __syncthreads drains
// vmcnt (sc1 stores at IF$ before any add), gsm loads bypass L1/L2.
// Everything else byte-identical to R12.

typedef __attribute__((ext_vector_type(4))) _Float16 half4;
typedef __attribute__((ext_vector_type(2))) _Float16 half2f;
typedef __attribute__((ext_vector_type(4))) float float4v;

#define HH 160
#define WW 160
#define NPIX (HH*WW)
#define NC 19
#define NG 5
#define SPAN 3
#define TR 8
#define TC 16
#define NPXT 128
#define LR 14              // TR + 2*SPAN
#define LC 22              // TC + 2*SPAN
#define LCP 24             // padded halo row stride (half4 units)
#define HSTRIDE (LR*LCP)   // 336
#define NHALO (LR*LC)      // 308
#define NRING 180          // NHALO - 8*16 interior
#define NBLK 200
#define NTHR 640
#define EPSF 1e-20f
#define MAGICV 0x5EEDF00Du

// bar layout (u32 words): [0]=magic; counters at word 32,64,...,256 (128B apart);
// release epoch at word 288.
#define BAR_CNT(k) (32 + (k)*32)
#define BAR_REL    288

#define SZ_A    30720
#define OFF_WB  SZ_A
#define SHM_SZ  (SZ_A + 25*128*8)   // 56,320

__device__ __forceinline__ float fast_rcp(float x) { return __builtin_amdgcn_rcpf(x); }

__device__ __forceinline__ float smx0(float q0, float q1) {
    const float m  = fmaxf(q0, q1);
    const float e0 = __expf(q0 - m);
    const float e1 = __expf(q1 - m);
    return e0 * fast_rcp(e0 + e1);
}

__global__ void __launch_bounds__(NTHR) crf_kernel(
        const float* __restrict__ u,
        const float* __restrict__ rgb,
        const float* __restrict__ sw,
        const float* __restrict__ bw,
        const float* __restrict__ compat,
        unsigned long long* __restrict__ gsmA,   // ping-pong sm0 fields
        unsigned long long* __restrict__ gsmB,
        unsigned* __restrict__ bar,
        float* __restrict__ out) {
    __shared__ __align__(16) char shm[SHM_SZ];
    __shared__ float Msh[960];                   // 20x48 rows [Ms|Mb|RS|pad]
    __shared__ float rowsum[NC];
    __shared__ int   diagflag;
    float4*   rgbL = (float4*)shm;               // prologue only
    half4*    smH  = (half4*)shm;                // per-iter sm0 halo (f16)
    float*    accF = (float*)shm;                // general-path epilogue
    unsigned* wbW  = (unsigned*)(shm + OFF_WB);
    const uint2* wbP = (const uint2*)(shm + OFF_WB);

    constexpr float WSPC[49] = {
        0.36787944f,0.48567179f,0.57375342f,0.60653066f,0.57375342f,0.48567179f,0.36787944f,
        0.48567179f,0.64118039f,0.75746513f,0.80073740f,0.75746513f,0.64118039f,0.48567179f,
        0.57375342f,0.75746513f,0.89483932f,0.94595947f,0.89483932f,0.75746513f,0.57375342f,
        0.60653066f,0.80073740f,0.94595947f,1.00000000f,0.94595947f,0.80073740f,0.60653066f,
        0.57375342f,0.75746513f,0.89483932f,0.94595947f,0.89483932f,0.75746513f,0.57375342f,
        0.48567179f,0.64118039f,0.75746513f,0.80073740f,0.75746513f,0.64118039f,0.48567179f,
        0.36787944f,0.48567179f,0.57375342f,0.60653066f,0.57375342f,0.48567179f,0.36787944f };

    const int tid = threadIdx.x;
    const int px  = tid & 127;
    const int g   = tid >> 7;
    const int r   = px >> 4, c = px & 15;
    const int ti0 = blockIdx.y * TR, tj0 = blockIdx.x * TC;
    const int gp  = (ti0 + r) * WW + (tj0 + c);
    const int ctr = (r + SPAN) * LCP + (c + SPAN);
    const int ku  = 4 * g;
    const int bid = blockIdx.y * 10 + blockIdx.x;    // 0..199

    // ---- barrier init handshake (ws poisoned 0xAA before every launch) ----
    if (bid == 0 && tid == 0) {
        #pragma unroll
        for (int k = 0; k < 8; ++k)
            __hip_atomic_store(&bar[BAR_CNT(k)], 0u, __ATOMIC_RELAXED, __HIP_MEMORY_SCOPE_AGENT);
        __hip_atomic_store(&bar[BAR_REL], 0u, __ATOMIC_RELAXED, __HIP_MEMORY_SCOPE_AGENT);
        __hip_atomic_store(&bar[0], MAGICV, __ATOMIC_RELEASE, __HIP_MEMORY_SCOPE_AGENT);
    }
    if (tid == 0) {
        diagflag = 1;
        while (__hip_atomic_load(&bar[0], __ATOMIC_ACQUIRE, __HIP_MEMORY_SCOPE_AGENT) != MAGICV)
            __builtin_amdgcn_s_sleep(2);
    }
    // rowsum[j] = sum_c (sw[j,c] + bw[j,c])
    if (tid < NC) {
        float rs = 0.0f;
        for (int cb = 0; cb < NC; ++cb) rs += sw[tid*NC + cb] + bw[tid*NC + cb];
        rowsum[tid] = rs;
    }
    __syncthreads();

    // ---- phase 0: M = [compat@sw | compat@bw | RS] into LDS, O(19)/entry ----
    for (int e = tid; e < 960; e += NTHR) {
        const int k = e / 48, cc2 = e % 48;
        float acc = 0.0f;
        if (k < NC) {
            if (cc2 < NC) {
                for (int j = 0; j < NC; ++j) acc += compat[k*NC + j] * sw[j*NC + cc2];
            } else if (cc2 >= 20 && cc2 < 20 + NC) {
                const int cb = cc2 - 20;
                for (int j = 0; j < NC; ++j) acc += compat[k*NC + j] * bw[j*NC + cb];
            } else if (cc2 == 40) {
                for (int j = 0; j < NC; ++j) acc += compat[k*NC + j] * rowsum[j];
            }
        }
        Msh[e] = acc;
        bool off = false;
        if (k < NC) {
            if (cc2 < NC && cc2 != k && acc != 0.0f) off = true;
            if (cc2 >= 20 && cc2 < 20 + NC && (cc2 - 20) != k && acc != 0.0f) off = true;
        }
        if (off) atomicAnd(&diagflag, 0);
    }
    __syncthreads();

    float dsv[4], dbv[4];
    #pragma unroll
    for (int i = 0; i < 4; ++i) {
        dsv[i] = Msh[(ku + i) * 48 + (ku + i)];
        dbv[i] = Msh[(ku + i) * 48 + 20 + (ku + i)];
    }
    const bool isdiag = (diagflag != 0);

    // ---- phase 1: rgb halo, both batches ----
    for (int e = tid; e < 2 * NHALO; e += NTHR) {
        const int bb = e / NHALO, pos = e % NHALO;
        const int hr = pos / LC, hc = pos % LC;
        const int yi = ti0 - SPAN + hr, xj = tj0 - SPAN + hc;
        float4 rv = make_float4(0.f, 0.f, 0.f, 0.f);
        if ((unsigned)yi < HH && (unsigned)xj < WW) {
            const float* p = rgb + ((size_t)(bb * NPIX) + yi * WW + xj) * 3;
            rv = make_float4(p[0]*(1.f/160.f), p[1]*(1.f/160.f), p[2]*(1.f/160.f), 1.f);
        }
        rgbL[(bb ? HSTRIDE : 0) + hr * LCP + hc] = rv;
    }
    __syncthreads();

    // ---- phase 2a: bilateral weights (tap-subset per group) -> LDS pairs ----
    {
        const float4 cv0 = rgbL[ctr];
        const float4 cv1 = rgbL[HSTRIDE + ctr];
        const int tapb = g * 10;
        const int ntap = (g == 4) ? 9 : 10;
        for (int i = 0; i < ntap; ++i) {
            const int t = tapb + i;
            const int dx = t / 7 - SPAN, dy = t % 7 - SPAN;
            const int n = ctr + dx * LCP + dy;
            const float4 nv0 = rgbL[n];
            const float4 nv1 = rgbL[HSTRIDE + n];
            const float wsm = __expf(-(float)(dx*dx + dy*dy) * (1.f/18.f)) * nv0.w;
            const float dr0 = cv0.x-nv0.x, dg0 = cv0.y-nv0.y, db0 = cv0.z-nv0.z;
            const float dr1 = cv1.x-nv1.x, dg1 = cv1.y-nv1.y, db1 = cv1.z-nv1.z;
            const float wb0 = wsm * __expf(-0.5f*(dr0*dr0+dg0*dg0+db0*db0));
            const float wb1 = wsm * __expf(-0.5f*(dr1*dr1+dg1*dg1+db1*db1));
            half2f hw = {(_Float16)wb0, (_Float16)wb1};
            unsigned uw; __builtin_memcpy(&uw, &hw, 4);
            wbW[(t >> 1) * 256 + px * 2 + (t & 1)] = uw;
        }
        if (g == 4) wbW[24 * 256 + px * 2 + 1] = 0u;
    }
    __syncthreads();

    // ---- phase 2b: per-pixel inverse norms ----
    float snI, bnI0, bnI1;
    {
        float sn = 0.f, bn0 = 0.f, bn1 = 0.f;
        #pragma unroll
        for (int t = 0; t < 49; ++t) {
            const unsigned uw = wbW[(t >> 1) * 256 + px * 2 + (t & 1)];
            half2f hw; __builtin_memcpy(&hw, &uw, 4);
            bn0 += (float)hw.x; bn1 += (float)hw.y;
            const int dx = t / 7 - SPAN, dy = t % 7 - SPAN;
            const int yi = ti0 + r + dx, xj = tj0 + c + dy;
            sn += (((unsigned)yi < HH) && ((unsigned)xj < WW)) ? WSPC[t] : 0.0f;
        }
        snI  = fast_rcp(sn + EPSF);
        bnI0 = fast_rcp(bn0 + EPSF);
        bnI1 = fast_rcp(bn1 + EPSF);
    }

    // ---- one-time: own unaries ----
    float uv0[4], uv1[4];
    #pragma unroll
    for (int i = 0; i < 4; ++i) {
        const int ch = 4*g + i;
        uv0[i] = (ch < NC) ? u[(size_t)gp * NC + ch] : 0.0f;
        uv1[i] = (ch < NC) ? u[((size_t)NPIX + gp) * NC + ch] : 0.0f;
    }

    for (int it = 0; it < 5; ++it) {
        if (it > 0) {
            // ---- two-level distributed barrier ----
            __syncthreads();             // drains vmcnt: gsm stores at IF$
            if (tid == 0) {
                __hip_atomic_fetch_add(&bar[BAR_CNT(bid & 7)], 1u,
                                       __ATOMIC_RELAXED, __HIP_MEMORY_SCOPE_AGENT);
                if (bid == 0) {
                    unsigned sum;
                    do {
                        sum = 0;
                        #pragma unroll
                        for (int k = 0; k < 8; ++k)
                            sum += __hip_atomic_load(&bar[BAR_CNT(k)],
                                                     __ATOMIC_RELAXED, __HIP_MEMORY_SCOPE_AGENT);
                        if (sum < (unsigned)(NBLK * it)) __builtin_amdgcn_s_sleep(2);
                    } while (sum < (unsigned)(NBLK * it));
                    __hip_atomic_store(&bar[BAR_REL], (unsigned)it,
                                       __ATOMIC_RELAXED, __HIP_MEMORY_SCOPE_AGENT);
                } else {
                    while (__hip_atomic_load(&bar[BAR_REL],
                                             __ATOMIC_RELAXED, __HIP_MEMORY_SCOPE_AGENT)
                           < (unsigned)it)
                        __builtin_amdgcn_s_sleep(2);
                }
            }
            __syncthreads();
        }

        // ---- stage sm0 halo ----
        const unsigned long long* gsrc = ((it & 1) ? gsmA : gsmB);
        if (it == 0) {
            #pragma unroll
            for (int k2 = 0; k2 < 3; ++k2) {
                const int e = tid + NTHR * k2;
                if (e < NG * NHALO) {
                    const int sg = e / NHALO, pos = e - sg * NHALO;
                    const int hr = pos / LC, hc = pos - hr * LC;
                    const int yi = ti0 - SPAN + hr, xj = tj0 - SPAN + hc;
                    half4 hv = (half4)(_Float16)0.0f;
                    if ((unsigned)yi < HH && (unsigned)xj < WW) {
                        const int p = yi * WW + xj;
                        const float* q0 = u + (size_t)p * NC;
                        const float* q1 = u + (size_t)(NPIX + p) * NC;
                        #pragma unroll
                        for (int i = 0; i < 4; ++i) {
                            const int ch = 4*sg + i;
                            const float a = (ch < NC) ? q0[ch] : 0.0f;
                            const float d = (ch < NC) ? q1[ch] : 0.0f;
                            hv[i] = (_Float16)smx0(a, d);
                        }
                    }
                    smH[sg * HSTRIDE + hr * LCP + hc] = hv;
                }
            }
        } else if (isdiag) {
            // ring only (interior self-written last epilogue)
            #pragma unroll
            for (int k2 = 0; k2 < 2; ++k2) {
                const int e = tid + NTHR * k2;
                if (e < NG * NRING) {
                    const int sg = e / NRING, re = e - sg * NRING;
                    int hr, hc;
                    if (re < 66)        { hr = re / 22;          hc = re % 22; }
                    else if (re < 132)  { const int t2 = re - 66;  hr = 11 + t2 / 22; hc = t2 % 22; }
                    else                { const int t2 = re - 132; hr = 3 + t2 / 6;
                                          const int s = t2 % 6;    hc = (s < 3) ? s : s + 16; }
                    const int yi = ti0 - SPAN + hr, xj = tj0 - SPAN + hc;
                    half4 hv = (half4)(_Float16)0.0f;
                    if ((unsigned)yi < HH && (unsigned)xj < WW) {
                        const unsigned long long raw =
                            __hip_atomic_load(&gsrc[sg * NPIX + yi * WW + xj],
                                              __ATOMIC_RELAXED, __HIP_MEMORY_SCOPE_AGENT);
                        __builtin_memcpy(&hv, &raw, 8);
                    }
                    smH[sg * HSTRIDE + hr * LCP + hc] = hv;
                }
            }
        } else {
            #pragma unroll
            for (int k2 = 0; k2 < 3; ++k2) {
                const int e = tid + NTHR * k2;
                if (e < NG * NHALO) {
                    const int sg = e / NHALO, pos = e - sg * NHALO;
                    const int hr = pos / LC, hc = pos - hr * LC;
                    const int yi = ti0 - SPAN + hr, xj = tj0 - SPAN + hc;
                    half4 hv = (half4)(_Float16)0.0f;
                    if ((unsigned)yi < HH && (unsigned)xj < WW) {
                        const unsigned long long raw =
                            __hip_atomic_load(&gsrc[sg * NPIX + yi * WW + xj],
                                              __ATOMIC_RELAXED, __HIP_MEMORY_SCOPE_AGENT);
                        __builtin_memcpy(&hv, &raw, 8);
                    }
                    smH[sg * HSTRIDE + hr * LCP + hc] = hv;
                }
            }
        }
        __syncthreads();

        // ---- 49 taps as 24 pairs + 1 ----
        float4v sAv = (float4v)0.0f, b0a = (float4v)0.0f, b1a = (float4v)0.0f;
        const half4* pl = smH + g * HSTRIDE;
        #pragma unroll
        for (int i = 0; i < 24; ++i) {
            const uint2 wp = wbP[i * 128 + px];
            #pragma unroll
            for (int s = 0; s < 2; ++s) {
                const int t = 2*i + s;
                const int dx = t / 7 - SPAN, dy = t % 7 - SPAN;
                half2f hw; __builtin_memcpy(&hw, s ? &wp.y : &wp.x, 4);
                const float w0 = (float)hw.x, w1 = (float)hw.y;
                const half4 v = pl[ctr + dx*LCP + dy];
                const float4v f = {(float)v[0], (float)v[1], (float)v[2], (float)v[3]};
                sAv += WSPC[t] * f;
                b0a += w0 * f;
                b1a += w1 * f;
            }
        }
        {   // tap 48
            const uint2 wp = wbP[24 * 128 + px];
            half2f hw; __builtin_memcpy(&hw, &wp.x, 4);
            const float w0 = (float)hw.x, w1 = (float)hw.y;
            const half4 v = pl[ctr + SPAN*LCP + SPAN];
            const float4v f = {(float)v[0], (float)v[1], (float)v[2], (float)v[3]};
            sAv += WSPC[48] * f;
            b0a += w0 * f;
            b1a += w1 * f;
        }

        if (isdiag) {
            float q0v[4], q1v[4];
            #pragma unroll
            for (int i = 0; i < 4; ++i) {
                const float sAn = sAv[i] * snI;
                const float b0n = b0a[i] * bnI0;
                const float b1x = b1a[i] * bnI1;
                q0v[i] = uv0[i] - dsv[i]*sAn - dbv[i]*b0n;
                q1v[i] = uv1[i] - (dsv[i] + dbv[i]) + dsv[i]*sAn + dbv[i]*b1x;
            }
            if (it == 4) {
                #pragma unroll
                for (int i = 0; i < 4; ++i) {
                    const int ch = 4*g + i;
                    if (ch < NC) {
                        out[(size_t)gp * NC + ch]          = q0v[i];
                        out[((size_t)NPIX + gp) * NC + ch] = q1v[i];
                    }
                }
            } else {
                half4 sh;
                #pragma unroll
                for (int i = 0; i < 4; ++i) sh[i] = (_Float16)smx0(q0v[i], q1v[i]);
                __syncthreads();               // all tap reads of smH complete
                smH[g * HSTRIDE + ctr] = sh;   // interior self-write for next iter
                unsigned long long u64; __builtin_memcpy(&u64, &sh, 8);
                unsigned long long* gdst = ((it & 1) ? gsmB : gsmA);
                __hip_atomic_store(&gdst[g * NPIX + gp], u64,
                                   __ATOMIC_RELAXED, __HIP_MEMORY_SCOPE_AGENT);
            }
        } else {
            float q0v[4], q1v[4];
            __syncthreads();   // smH dead -> region A becomes accF
            #pragma unroll
            for (int i = 0; i < 4; ++i) {
                accF[(4*g + i) * NPXT + px]      = sAv[i] * snI;
                accF[(20 + 4*g + i) * NPXT + px] = b0a[i] * bnI0;
                accF[(40 + 4*g + i) * NPXT + px] = b1a[i] * bnI1;
            }
            __syncthreads();
            float t1[4] = {0,0,0,0}, t2[4] = {0,0,0,0}, t3[4] = {0,0,0,0};
            #pragma unroll
            for (int cc = 0; cc < 20; ++cc) {
                const float sv  = accF[cc * NPXT + px];
                const float b0v = accF[(20 + cc) * NPXT + px];
                const float b1v = accF[(40 + cc) * NPXT + px];
                #pragma unroll
                for (int i = 0; i < 4; ++i) {
                    const float* mk = Msh + (ku + i) * 48;
                    t1[i] += mk[cc] * sv;
                    t2[i] += mk[20 + cc] * b0v;
                    t3[i] += mk[20 + cc] * b1v;
                }
            }
            #pragma unroll
            for (int i = 0; i < 4; ++i) {
                const float rs = Msh[(ku + i) * 48 + 40];
                q0v[i] = uv0[i] - t1[i] - t2[i];
                q1v[i] = uv1[i] - rs + t1[i] + t3[i];
            }
            if (it == 4) {
                #pragma unroll
                for (int i = 0; i < 4; ++i) {
                    const int ch = 4*g + i;
                    if (ch < NC) {
                        out[(size_t)gp * NC + ch]          = q0v[i];
                        out[((size_t)NPIX + gp) * NC + ch] = q1v[i];
                    }
                }
            } else {
                half4 sh;
                #pragma unroll
                for (int i = 0; i < 4; ++i) sh[i] = (_Float16)smx0(q0v[i], q1v[i]);
                unsigned long long u64; __builtin_memcpy(&u64, &sh, 8);
                unsigned long long* gdst = ((it & 1) ? gsmB : gsmA);
                __hip_atomic_store(&gdst[g * NPIX + gp], u64,
                                   __ATOMIC_RELAXED, __HIP_MEMORY_SCOPE_AGENT);
            }
        }
    }
}

extern "C" void kernel_launch(void* const* d_in, const int* in_sizes, int n_in,
                              void* d_out, int out_size, void* d_ws, size_t ws_size,
                              hipStream_t stream) {
    const float* u      = (const float*)d_in[0];
    const float* rgb    = (const float*)d_in[1];
    const float* sw     = (const float*)d_in[2];
    const float* bw     = (const float*)d_in[3];
    const float* compat = (const float*)d_in[4];
    float* out = (float*)d_out;

    unsigned long long* gsmA = (unsigned long long*)d_ws;              // 1,024,000 B
    unsigned long long* gsmB = (unsigned long long*)((char*)d_ws + 1024000);
    unsigned* bar = (unsigned*)((char*)d_ws + 2048000);                // ~1.2 KB used

    crf_kernel<<<dim3(WW/TC, HH/TR, 1), dim3(NTHR), 0, stream>>>(
        u, rgb, sw, bw, compat, gsmA, gsmB, bar, out);
}